// Round 2
// baseline (239.426 us; speedup 1.0000x reference)
//
#include <hip/hip_runtime.h>

// NMS3D: x (4,2,64,256,256) f32, 3x3x3 neighborhood-max excluding center,
// edge padding == index clamping.
//
// R6 = R5 + full residency + 2-deep async pipeline:
//  - DC=16 -> grid 1024 = exactly 4 blocks/CU all co-resident (40KiB LDS x4,
//    512 thr x4 = 2048). No block churn; max TLP against load latency.
//  - NBUF=4 slice buffers, global_load_lds prefetch depth 2 (slices t+1 AND
//    t+2 in flight), exact counted vmcnt(N) per unrolled iteration -- never
//    a vmcnt(0) drain in the main loop.
//  - XCD-aware linear-id decode: volume n = bid&7 -> each XCD streams one
//    16MB volume; h/z-neighbor blocks co-resident -> halo reads hit L2.

constexpr int D_   = 64;
constexpr int H_   = 256;
constexpr int W_   = 256;
constexpr int HW_  = H_ * W_;
constexpr int NVOL = 8;         // B * CH
constexpr int DC   = 16;        // depth slices emitted per block
constexpr int RY   = 8;         // output rows per block
constexpr int RS   = RY + 2;    // rows staged per slice
constexpr int NBUF = 4;         // LDS slice buffers (depth-2 rotation)
constexpr int S    = DC + 2;    // slices touched: z0-1 .. z0+DC

__device__ __forceinline__ float f3(float a, float b, float c) {
    return fmaxf(fmaxf(a, b), c);
}

// async global->LDS, 16B per lane; LDS dest = wave-uniform base + lane*16
__device__ __forceinline__ void gload16(const float* g, float* l) {
    __builtin_amdgcn_global_load_lds(
        (const __attribute__((address_space(1))) void*)g,
        (__attribute__((address_space(3))) void*)l,
        16, 0, 0);
}

// counted vmcnt wait; n is compile-time constant after unroll -> switch folds
__device__ __forceinline__ void vmwait(int n) {
    switch (n) {
    case 0: asm volatile("s_waitcnt vmcnt(0)" ::: "memory"); break;
    case 1: asm volatile("s_waitcnt vmcnt(1)" ::: "memory"); break;
    case 2: asm volatile("s_waitcnt vmcnt(2)" ::: "memory"); break;
    case 3: asm volatile("s_waitcnt vmcnt(3)" ::: "memory"); break;
    case 4: asm volatile("s_waitcnt vmcnt(4)" ::: "memory"); break;
    case 5: asm volatile("s_waitcnt vmcnt(5)" ::: "memory"); break;
    case 6: asm volatile("s_waitcnt vmcnt(6)" ::: "memory"); break;
    default: asm volatile("s_waitcnt vmcnt(0)" ::: "memory"); break;
    }
}

__global__ __launch_bounds__(512, 8)
void nms3d(const float* __restrict__ x, float* __restrict__ out)
{
    __shared__ float lds[NBUF][RS * W_];   // 4 x 10 KiB = 40 KiB

    const int tx = threadIdx.x;            // 0..63 lane; wave covers one row
    const int ty = threadIdx.y;            // 0..7  wave id

    // XCD-aware decode of a 1-D grid: consecutive ids round-robin XCDs,
    // so volume n == XCD id; same-volume blocks (adjacent h/z) co-reside.
    const int bid  = blockIdx.x;           // 0..1023
    const int n    = bid & 7;              // volume -> XCD
    const int rest = bid >> 3;             // 0..127
    const int z0   = (rest & 3) * DC;      // 4 z-chunks
    const int h0   = (rest >> 2) * RY;     // 32 h-strips
    const int h    = h0 + ty;
    const int c    = tx << 2;

    const float* __restrict__ base  = x   + (size_t)n * D_ * HW_;
    float* __restrict__       obase = out + (size_t)n * D_ * HW_;

    // wave ty stages LDS row ty = clamp(h0-1+ty); waves 0,1 also rows 8,9
    const int grA = min(max(h0 - 1 + ty, 0), H_ - 1);
    const int grB = min(max(h0 - 1 + RY + ty, 0), H_ - 1);
    const float* gA = base + (size_t)grA * W_ + c;
    const float* gB = base + (size_t)grB * W_ + c;

    auto stage = [&](int t) {
        const int zc = min(max(z0 - 1 + t, 0), D_ - 1);
        const size_t zo = (size_t)zc * HW_;
        float* lp = &lds[t & (NBUF - 1)][0];
        gload16(gA + zo, lp + ty * W_);
        if (ty < 2) gload16(gB + zo, lp + (RY + ty) * W_);
    };

    stage(0);
    stage(1);   // prologue: 2 slices in flight

    // rolling depth state
    float4 vm9_pp = {0,0,0,0};  // vmax9[z-2]
    float4 vm9_p  = {0,0,0,0};  // vmax9[z-1]
    float4 cr8_p  = {0,0,0,0};  // cross8[z-1]
    float4 vprev  = {0,0,0,0};  // v[z-1]

#pragma unroll
    for (int t = 0; t < S; ++t) {
        if (t + 2 < S) stage(t + 2);       // keep 2 slices in flight

        // wait exactly for slice-t loads (issued 2 iterations ago).
        // N = #VMEM ops (loads+stores) provably issued after them.
        int nhi, nlo;                       // ty>=2 (1 load/it) / ty<2 (2)
        if      (t <= 2)     { nhi = 2; nlo = 4; }
        else if (t == 3)     { nhi = 3; nlo = 5; }
        else if (t <= S - 3) { nhi = 4; nlo = 6; }
        else if (t == S - 2) { nhi = 3; nlo = 4; }
        else                 { nhi = 2; nlo = 2; }
        vmwait(ty < 2 ? nlo : nhi);

        __builtin_amdgcn_s_barrier();       // raw: no implicit vmcnt(0)
        asm volatile("" ::: "memory");      // keep LDS reads below barrier

        // slice zi = z0-1+t, rows h-1,h,h+1 from LDS (conflict-free b128)
        const float* p = &lds[t & (NBUF - 1)][0];
        const float4 a0 = *(const float4*)(p + (ty    ) * W_ + c);
        const float4 b0 = *(const float4*)(p + (ty + 1) * W_ + c);
        const float4 d0 = *(const float4*)(p + (ty + 2) * W_ + c);

        float4 va;
        va.x = fmaxf(a0.x, d0.x); va.y = fmaxf(a0.y, d0.y);
        va.z = fmaxf(a0.z, d0.z); va.w = fmaxf(a0.w, d0.w);

        float vaL = __shfl_up(va.w, 1);   if (tx == 0)  vaL = va.x;
        float vaR = __shfl_down(va.x, 1); if (tx == 63) vaR = va.w;
        float bL  = __shfl_up(b0.w, 1);   if (tx == 0)  bL  = b0.x;
        float bR  = __shfl_down(b0.x, 1); if (tx == 63) bR  = b0.w;

        float4 hv, nb;
        hv.x = f3(vaL, va.x, va.y);  hv.y = f3(va.x, va.y, va.z);
        hv.z = f3(va.y, va.z, va.w); hv.w = f3(va.z, va.w, vaR);
        nb.x = fmaxf(bL,  b0.y);  nb.y = fmaxf(b0.x, b0.z);
        nb.z = fmaxf(b0.y, b0.w); nb.w = fmaxf(b0.z, bR);

        float4 c8, cur;                      // cross8[zi], vmax9[zi]
        c8.x  = fmaxf(hv.x, nb.x); c8.y  = fmaxf(hv.y, nb.y);
        c8.z  = fmaxf(hv.z, nb.z); c8.w  = fmaxf(hv.w, nb.w);
        cur.x = fmaxf(c8.x, b0.x); cur.y = fmaxf(c8.y, b0.y);
        cur.z = fmaxf(c8.z, b0.z); cur.w = fmaxf(c8.w, b0.w);

        if (t >= 2) {
            // emit out[zi-1]: max_nc = max(vmax9[zi-2], cross8[zi-1], vmax9[zi])
            const int zi = z0 - 1 + t;
            float4 mx, o;
            mx.x = f3(vm9_pp.x, cr8_p.x, cur.x);
            mx.y = f3(vm9_pp.y, cr8_p.y, cur.y);
            mx.z = f3(vm9_pp.z, cr8_p.z, cur.z);
            mx.w = f3(vm9_pp.w, cr8_p.w, cur.w);
            o.x = vprev.x > mx.x ? vprev.x : 0.0f;
            o.y = vprev.y > mx.y ? vprev.y : 0.0f;
            o.z = vprev.z > mx.z ? vprev.z : 0.0f;
            o.w = vprev.w > mx.w ? vprev.w : 0.0f;
            *(float4*)(obase + (size_t)(zi - 1) * HW_ + (size_t)h * W_ + c) = o;
        }
        vm9_pp = vm9_p; vm9_p = cur; cr8_p = c8; vprev = b0;
    }
}

extern "C" void kernel_launch(void* const* d_in, const int* in_sizes, int n_in,
                              void* d_out, int out_size, void* d_ws, size_t ws_size,
                              hipStream_t stream)
{
    const float* x = (const float*)d_in[0];
    float* out = (float*)d_out;
    dim3 block(64, RY, 1);                 // 512 threads = 8 waves
    dim3 grid(NVOL * (D_ / DC) * (H_ / RY), 1, 1);   // 1024 blocks, 1-D
    nms3d<<<grid, block, 0, stream>>>(x, out);
}

// Round 4
// 238.728 us; speedup vs baseline: 1.0029x; 1.0029x over previous
//
#include <hip/hip_runtime.h>

// NMS3D: x (4,2,64,256,256) f32, 3x3x3 neighborhood-max excluding center,
// edge padding == index clamping.
//
// R8 = R7 with the nontemporal-store compile fix (native ext_vector float4).
//  - NT output stores: output (134MB, never re-read) doesn't allocate in
//    L2/L3 -> 134MB input stays L3-resident. Theory: in+out = 268MB > 256MB
//    L3 caused the eviction storm seen as FETCH_SIZE=73MB; HBM-latency reads
//    at fixed per-wave concurrency pinned read BW ~2.2-2.5 TB/s in ALL
//    prior structures.
//  - Prefetch depth 3 (NBUF=5), exact counted vmcnt(N) per unrolled t;
//    never vmcnt(0) inside the main loop.

constexpr int D_   = 64;
constexpr int H_   = 256;
constexpr int W_   = 256;
constexpr int HW_  = H_ * W_;
constexpr int NVOL = 8;         // B * CH
constexpr int DC   = 16;        // depth slices emitted per block
constexpr int RY   = 8;         // output rows per block
constexpr int RS   = RY + 2;    // rows staged per slice
constexpr int NBUF = 5;         // LDS slice buffers (depth-3 rotation)
constexpr int S    = DC + 2;    // slices touched: z0-1 .. z0+DC
constexpr int PF   = 3;         // prefetch depth

typedef float f32x4 __attribute__((ext_vector_type(4)));  // NT-store-compatible

__device__ __forceinline__ float f3(float a, float b, float c) {
    return fmaxf(fmaxf(a, b), c);
}

// async global->LDS, 16B per lane; LDS dest = wave-uniform base + lane*16
__device__ __forceinline__ void gload16(const float* g, float* l) {
    __builtin_amdgcn_global_load_lds(
        (const __attribute__((address_space(1))) void*)g,
        (__attribute__((address_space(3))) void*)l,
        16, 0, 0);
}

// counted vmcnt wait; n is a compile-time constant after unroll
__device__ __forceinline__ void vmwait(int n) {
    switch (n) {
    case 0: asm volatile("s_waitcnt vmcnt(0)" ::: "memory"); break;
    case 1: asm volatile("s_waitcnt vmcnt(1)" ::: "memory"); break;
    case 2: asm volatile("s_waitcnt vmcnt(2)" ::: "memory"); break;
    case 3: asm volatile("s_waitcnt vmcnt(3)" ::: "memory"); break;
    case 4: asm volatile("s_waitcnt vmcnt(4)" ::: "memory"); break;
    case 5: asm volatile("s_waitcnt vmcnt(5)" ::: "memory"); break;
    case 6: asm volatile("s_waitcnt vmcnt(6)" ::: "memory"); break;
    case 7: asm volatile("s_waitcnt vmcnt(7)" ::: "memory"); break;
    case 8: asm volatile("s_waitcnt vmcnt(8)" ::: "memory"); break;
    case 9: asm volatile("s_waitcnt vmcnt(9)" ::: "memory"); break;
    default: asm volatile("s_waitcnt vmcnt(0)" ::: "memory"); break;
    }
}

// #VMEM ops issued after slice-t's stage loads, per wave class.
// Prologue stages 0..2; iter u stages u+3 (u<=S-4); NT store from u>=2.
__device__ __forceinline__ constexpr int wait_lo(int t) {  // ty<2: 2 loads/stage
    if (t <= 2)      return 6;
    if (t == 3)      return 7;
    if (t == 4)      return 8;
    if (t <= S - 4)  return 9;          // steady state
    if (t == S - 3)  return 7;
    if (t == S - 2)  return 5;
    return 3;
}
__device__ __forceinline__ constexpr int wait_hi(int t) {  // ty>=2: 1 load/stage
    if (t <= 2)      return 3;
    if (t == 3)      return 4;
    if (t == 4)      return 5;
    if (t <= S - 4)  return 6;
    if (t == S - 3)  return 5;
    if (t == S - 2)  return 4;
    return 3;
}

__global__ __launch_bounds__(512, 6)
void nms3d(const float* __restrict__ x, float* __restrict__ out)
{
    __shared__ float lds[NBUF][RS * W_];   // 5 x 10 KiB = 50 KiB -> 3 blocks/CU

    const int tx = threadIdx.x;            // 0..63 lane; wave covers one row
    const int ty = threadIdx.y;            // 0..7  wave id

    // XCD-aware decode: volume n == XCD id; same-volume blocks co-reside.
    const int bid  = blockIdx.x;           // 0..1023
    const int n    = bid & 7;
    const int rest = bid >> 3;             // 0..127
    const int z0   = (rest & 3) * DC;      // 4 z-chunks
    const int h0   = (rest >> 2) * RY;     // 32 h-strips
    const int h    = h0 + ty;
    const int c    = tx << 2;

    const float* __restrict__ base  = x   + (size_t)n * D_ * HW_;
    float* __restrict__       obase = out + (size_t)n * D_ * HW_;

    // wave ty stages LDS row ty = clamp(h0-1+ty); waves 0,1 also rows 8,9
    const int grA = min(max(h0 - 1 + ty, 0), H_ - 1);
    const int grB = min(max(h0 - 1 + RY + ty, 0), H_ - 1);
    const float* gA = base + (size_t)grA * W_ + c;
    const float* gB = base + (size_t)grB * W_ + c;

    auto stage = [&](int t) {
        const int zc = min(max(z0 - 1 + t, 0), D_ - 1);
        const size_t zo = (size_t)zc * HW_;
        float* lp = &lds[t % NBUF][0];
        gload16(gA + zo, lp + ty * W_);
        if (ty < 2) gload16(gB + zo, lp + (RY + ty) * W_);
    };

    stage(0);
    stage(1);
    stage(2);   // prologue: 3 slices in flight

    // rolling depth state
    float4 vm9_pp = {0,0,0,0};  // vmax9[z-2]
    float4 vm9_p  = {0,0,0,0};  // vmax9[z-1]
    float4 cr8_p  = {0,0,0,0};  // cross8[z-1]
    float4 vprev  = {0,0,0,0};  // v[z-1]

#pragma unroll
    for (int t = 0; t < S; ++t) {
        if (t + PF < S) stage(t + PF);     // keep 3 slices in flight

        vmwait(ty < 2 ? wait_lo(t) : wait_hi(t));   // slice-t loads complete
        __builtin_amdgcn_s_barrier();       // raw: no implicit vmcnt(0) drain
        asm volatile("" ::: "memory");      // keep LDS reads below barrier

        // slice zi = z0-1+t, rows h-1,h,h+1 from LDS (conflict-free b128)
        const float* p = &lds[t % NBUF][0];
        const float4 a0 = *(const float4*)(p + (ty    ) * W_ + c);
        const float4 b0 = *(const float4*)(p + (ty + 1) * W_ + c);
        const float4 d0 = *(const float4*)(p + (ty + 2) * W_ + c);

        float4 va;
        va.x = fmaxf(a0.x, d0.x); va.y = fmaxf(a0.y, d0.y);
        va.z = fmaxf(a0.z, d0.z); va.w = fmaxf(a0.w, d0.w);

        float vaL = __shfl_up(va.w, 1);   if (tx == 0)  vaL = va.x;
        float vaR = __shfl_down(va.x, 1); if (tx == 63) vaR = va.w;
        float bL  = __shfl_up(b0.w, 1);   if (tx == 0)  bL  = b0.x;
        float bR  = __shfl_down(b0.x, 1); if (tx == 63) bR  = b0.w;

        float4 hv, nb;
        hv.x = f3(vaL, va.x, va.y);  hv.y = f3(va.x, va.y, va.z);
        hv.z = f3(va.y, va.z, va.w); hv.w = f3(va.z, va.w, vaR);
        nb.x = fmaxf(bL,  b0.y);  nb.y = fmaxf(b0.x, b0.z);
        nb.z = fmaxf(b0.y, b0.w); nb.w = fmaxf(b0.z, bR);

        float4 c8, cur;                      // cross8[zi], vmax9[zi]
        c8.x  = fmaxf(hv.x, nb.x); c8.y  = fmaxf(hv.y, nb.y);
        c8.z  = fmaxf(hv.z, nb.z); c8.w  = fmaxf(hv.w, nb.w);
        cur.x = fmaxf(c8.x, b0.x); cur.y = fmaxf(c8.y, b0.y);
        cur.z = fmaxf(c8.z, b0.z); cur.w = fmaxf(c8.w, b0.w);

        if (t >= 2) {
            // emit out[zi-1]: max_nc = max(vmax9[zi-2], cross8[zi-1], vmax9[zi])
            const int zi = z0 - 1 + t;
            float4 mx;
            mx.x = f3(vm9_pp.x, cr8_p.x, cur.x);
            mx.y = f3(vm9_pp.y, cr8_p.y, cur.y);
            mx.z = f3(vm9_pp.z, cr8_p.z, cur.z);
            mx.w = f3(vm9_pp.w, cr8_p.w, cur.w);
            f32x4 o;
            o.x = vprev.x > mx.x ? vprev.x : 0.0f;
            o.y = vprev.y > mx.y ? vprev.y : 0.0f;
            o.z = vprev.z > mx.z ? vprev.z : 0.0f;
            o.w = vprev.w > mx.w ? vprev.w : 0.0f;
            // NT store (native vec type): output skips L2/L3 allocation
            f32x4* dst = (f32x4*)(obase + (size_t)(zi - 1) * HW_ +
                                  (size_t)h * W_ + c);
            __builtin_nontemporal_store(o, dst);
        }
        vm9_pp = vm9_p; vm9_p = cur; cr8_p = c8; vprev = b0;
    }
}

extern "C" void kernel_launch(void* const* d_in, const int* in_sizes, int n_in,
                              void* d_out, int out_size, void* d_ws, size_t ws_size,
                              hipStream_t stream)
{
    const float* x = (const float*)d_in[0];
    float* out = (float*)d_out;
    dim3 block(64, RY, 1);                 // 512 threads = 8 waves
    dim3 grid(NVOL * (D_ / DC) * (H_ / RY), 1, 1);   // 1024 blocks, 1-D
    nms3d<<<grid, block, 0, stream>>>(x, out);
}